// Round 1
// baseline (246.818 us; speedup 1.0000x reference)
//
#include <hip/hip_runtime.h>
#include <hip/hip_bf16.h>

// Established facts (R1..R8 on HW):
//  - Harness I/O is FP32; ~170us of dur_us is fixed harness overhead (incl. 512MB
//    workspace re-poison fills at ~77us visible in rocprof top-5).
//  - MFMA 16x16x32_bf16 layouts verified in-harness (R6/R7/R8):
//      A[m=lane&15][k=(lane>>4)*8+j], B[n=lane&15][k=(lane>>4)*8+j],
//      C/D col=lane&15, row=(lane>>4)*4+reg.
//  - R9 (this round): node_pers was 16 iters x 5 barriers = 80 barrier rounds/block
//    with only ~160 MFMA-cycles between barriers. Restructure to 2-graph (64-row)
//    tiles, separate h buffer -> 2 barriers/tile (16 rounds), L2 with full-K per
//    wave (no partial-reduce barrier), waves 4-7 overlap L2 with next-tile staging.
//    Also: conditional last prefetch (kill 8MB dead reads), wpack+glist fused.

#define G_   4096
#define NPG_ 32
#define NN_  (G_*NPG_)     // 131072
#define D_   256
#define SH_  256
#define HDG_ 50
#define HDN_ 3

// output layout (fp32 elements): g_head | n_head | g_var | n_var
#define OFF_GH 0
#define OFF_NH (G_*HDG_)             // 204800
#define OFF_GV (OFF_NH + NN_*HDN_)   // 598016
#define OFF_NV (OFF_GV + G_*HDG_)    // 802816

typedef short v8s __attribute__((ext_vector_type(8)));   // 8 bf16 = 16 B (MFMA A/B frag)
typedef short v4s __attribute__((ext_vector_type(4)));
typedef float v4f __attribute__((ext_vector_type(4)));   // MFMA C/D frag

__device__ __forceinline__ float bfu2f(unsigned short u) {
    return __uint_as_float(((unsigned int)u) << 16);
}
__device__ __forceinline__ unsigned short f2bfu(float v) {
    __hip_bfloat16 b = __float2bfloat16(v);
    return *reinterpret_cast<unsigned short*>(&b);
}

#define MFMA16(a, b, c) __builtin_amdgcn_mfma_f32_16x16x32_bf16((a), (b), (c), 0, 0, 0)

// ---- fused prep: weight packing (blocks 0..1311) + per-branch graph lists (block 1312) ----
__global__ __launch_bounds__(256) void prep(const float* __restrict__ Wn1,
                                            const float* __restrict__ Wgs,
                                            const float* __restrict__ Wgh,
                                            const float* __restrict__ Wn2,
                                            unsigned short* __restrict__ wout,
                                            const int* __restrict__ dsname,
                                            int* __restrict__ glist,    // [2][4096]
                                            int* __restrict__ gcnt) {   // [2]
    const int blk = blockIdx.x;
    const int t = threadIdx.x;
    if (blk < 1312) {
        const int idx = blk * 256 + t;   // 0 .. 335871
        float v;
        if (idx < 131072) {
            const int b = idx >> 16, rem = idx & 65535, s = rem >> 8, d = rem & 255;
            v = Wn1[b * 65536 + d * 256 + s];
        } else if (idx < 262144) {
            const int i2 = idx - 131072;
            const int np = i2 >> 8, d = i2 & 255;
            v = Wgs[(np >> 8) * 65536 + d * 256 + (np & 255)];
        } else if (idx < 327680) {
            const int i3 = idx - 262144;
            const int npp = i3 >> 8, k = i3 & 255;
            const int b = npp >> 7, c = npp & 127;
            v = (c < 100) ? Wgh[b * 25600 + k * 100 + c] : 0.f;
        } else {
            const int i4 = idx - 327680;
            const int b = i4 >> 12, rem = i4 & 4095, n = rem >> 8, k = rem & 255;
            v = (n < 6) ? Wn2[b * 1536 + k * 6 + n] : 0.f;
        }
        wout[idx] = f2bfu(v);
    } else {
        __shared__ int cnt[2];
        if (t < 2) cnt[t] = 0;
        __syncthreads();
        for (int i = 0; i < 16; i++) {
            const int g = i * 256 + t;
            const int b = dsname[g];
            const int slot = atomicAdd(&cnt[b], 1);
            glist[b * G_ + slot] = g;
        }
        __syncthreads();
        if (t < 2) gcnt[t] = cnt[t];
    }
}

// ---- persistent node kernel: 256 blocks x 512 threads (8 waves), branch = blockIdx&1.
// 2-graph (64-row) tiles; xs (input) and hs (hidden) are SEPARATE LDS buffers ->
// only 2 barriers per tile. L2 MLP: waves 0..3 each own one 16-row m-tile with
// full K=256 from registers -> direct global stores, no partial-reduce barrier.
// Waves 4..7 overlap L2 with the next tile's convert+prefetch. ----
__global__ __launch_bounds__(512) void node_pers2(const float* __restrict__ x,
                                                  const int* __restrict__ glist,
                                                  const int* __restrict__ gcnt,
                                                  const unsigned short* __restrict__ Wn1T,
                                                  const float* __restrict__ bn1,
                                                  const unsigned short* __restrict__ Wn2b,
                                                  const float* __restrict__ bn2,
                                                  unsigned short* __restrict__ xg,
                                                  float* __restrict__ out) {
    __shared__ __align__(16) unsigned short xs[64 * 264];   // 33.8 KB bf16 x-tile
    __shared__ __align__(16) unsigned short hs[64 * 264];   // 33.8 KB bf16 hidden
    __shared__ __align__(16) float red[16 * 256];           // 16 KB mean partials
    const int t = threadIdx.x;
    const int wave = t >> 6, lane = t & 63;
    const int l15 = lane & 15, quad = lane >> 4;
    const int br = blockIdx.x & 1;
    const int bslot = blockIdx.x >> 1;        // 0..127
    const int cnt = gcnt[br];
    const int ntile = (cnt + 1) >> 1;

    // wave's hidden columns: base_n + nt*16 + l15 (nt<2); union over 8 waves = 0..255
    const int base_n = (wave & 1) * 128 + (wave >> 1) * 32;

    // L1 B fragments + bias: loaded ONCE per block
    v8s B1[2][8];
    float bias1[2];
    #pragma unroll
    for (int nt = 0; nt < 2; nt++) {
        const unsigned short* bp = Wn1T + br * 65536 + (base_n + nt * 16 + l15) * 256 + quad * 8;
        #pragma unroll
        for (int kt = 0; kt < 8; kt++) B1[nt][kt] = *(const v8s*)(bp + kt * 32);
        bias1[nt] = bn1[br * 256 + base_n + nt * 16 + l15];
    }

    // L2 B fragments: full K=256 (8 kt) for the single 16-col n-tile; once per block
    v8s B2[8];
    {
        const unsigned short* bp = Wn2b + br * 4096 + l15 * 256 + quad * 8;
        #pragma unroll
        for (int kt = 0; kt < 8; kt++) B2[kt] = *(const v8s*)(bp + kt * 32);
    }
    float bias2 = 0.f;
    if (l15 < 6) bias2 = bn2[br * 6 + l15];

    // load mapping: thread t covers row r0+8k (k=0..7), dword cols colb..colb+3.
    // k<4 -> graph A (rows 0..31), k>=4 -> graph B (rows 32..63). Fully coalesced:
    // a wave reads one full 1KB row per k.
    const int r0 = t >> 6;           // 0..7 (== wave)
    const int colb = (t & 63) * 4;   // 0..252

    float4 pv[8];
    int ga = 0, gb = 0;
    if (bslot < ntile) {
        const int i0 = 2 * bslot, i1 = i0 + 1;
        ga = glist[br * G_ + i0];                          // i0 < cnt always (ntile def)
        gb = glist[br * G_ + ((i1 < cnt) ? i1 : cnt - 1)]; // clamp: benign duplicate
        const float* xa = x + (size_t)ga * 8192 + r0 * 256 + colb;
        const float* xb = x + (size_t)gb * 8192 + r0 * 256 + colb;
        #pragma unroll
        for (int k = 0; k < 4; k++) {
            pv[k]     = *(const float4*)(xa + k * 2048);
            pv[4 + k] = *(const float4*)(xb + k * 2048);
        }
    }

    for (int ti = bslot; ti < ntile; ti += 128) {
        const int gA = ga, gB = gb;

        // 1) convert pv -> xs (bf16) + fp32 mean partials -> red
        float4 sa = make_float4(0.f, 0.f, 0.f, 0.f);
        float4 sb = make_float4(0.f, 0.f, 0.f, 0.f);
        #pragma unroll
        for (int k = 0; k < 4; k++) {
            const float4 va = pv[k], vb = pv[4 + k];
            sa.x += va.x; sa.y += va.y; sa.z += va.z; sa.w += va.w;
            sb.x += vb.x; sb.y += vb.y; sb.z += vb.z; sb.w += vb.w;
            v4s bva, bvb;
            bva[0] = (short)f2bfu(va.x); bva[1] = (short)f2bfu(va.y);
            bva[2] = (short)f2bfu(va.z); bva[3] = (short)f2bfu(va.w);
            bvb[0] = (short)f2bfu(vb.x); bvb[1] = (short)f2bfu(vb.y);
            bvb[2] = (short)f2bfu(vb.z); bvb[3] = (short)f2bfu(vb.w);
            *(v4s*)(&xs[(r0 + 8 * k) * 264 + colb])      = bva;
            *(v4s*)(&xs[(32 + r0 + 8 * k) * 264 + colb]) = bvb;
        }
        *(float4*)(&red[r0 * 256 + colb])       = sa;
        *(float4*)(&red[(8 + r0) * 256 + colb]) = sb;

        // 2) prefetch NEXT tile (latency hidden under MFMA phase); skip dead last fetch
        {
            const int tn = ti + 128;
            if (tn < ntile) {
                const int i0 = 2 * tn, i1 = i0 + 1;
                ga = glist[br * G_ + i0];
                gb = glist[br * G_ + ((i1 < cnt) ? i1 : cnt - 1)];
                const float* xa = x + (size_t)ga * 8192 + r0 * 256 + colb;
                const float* xb = x + (size_t)gb * 8192 + r0 * 256 + colb;
                #pragma unroll
                for (int k = 0; k < 4; k++) {
                    pv[k]     = *(const float4*)(xa + k * 2048);
                    pv[4 + k] = *(const float4*)(xb + k * 2048);
                }
            }
        }
        __syncthreads();   // A: xs + red visible

        // 3) mean -> xg (both graphs; all 512 threads)
        {
            const int g = t >> 8, c = t & 255;
            float m = 0.f;
            #pragma unroll
            for (int r = 0; r < 8; r++) m += red[(g * 8 + r) * 256 + c];
            xg[(size_t)(g ? gB : gA) * 256 + c] = f2bfu(m * (1.0f / NPG_));
        }

        // 4) L1 MFMA: M=64 (4 m-tiles), wave's N=32 (2 n-tiles), K=256; B in regs
        v4f acc[4][2];
        #pragma unroll
        for (int mt = 0; mt < 4; mt++)
            #pragma unroll
            for (int nt = 0; nt < 2; nt++) acc[mt][nt] = (v4f){0.f, 0.f, 0.f, 0.f};
        #pragma unroll
        for (int kt = 0; kt < 8; kt++) {
            const int ko = kt * 32 + quad * 8;
            v8s a0 = *(const v8s*)(&xs[(     l15) * 264 + ko]);
            v8s a1 = *(const v8s*)(&xs[(16 + l15) * 264 + ko]);
            v8s a2 = *(const v8s*)(&xs[(32 + l15) * 264 + ko]);
            v8s a3 = *(const v8s*)(&xs[(48 + l15) * 264 + ko]);
            #pragma unroll
            for (int nt = 0; nt < 2; nt++) {
                acc[0][nt] = MFMA16(a0, B1[nt][kt], acc[0][nt]);
                acc[1][nt] = MFMA16(a1, B1[nt][kt], acc[1][nt]);
                acc[2][nt] = MFMA16(a2, B1[nt][kt], acc[2][nt]);
                acc[3][nt] = MFMA16(a3, B1[nt][kt], acc[3][nt]);
            }
        }

        // 5) bias + ReLU -> hs (bf16)
        #pragma unroll
        for (int nt = 0; nt < 2; nt++) {
            const int col = base_n + nt * 16 + l15;
            #pragma unroll
            for (int mt = 0; mt < 4; mt++)
                #pragma unroll
                for (int r = 0; r < 4; r++) {
                    const int row = mt * 16 + quad * 4 + r;
                    const float v = acc[mt][nt][r] + bias1[nt];
                    hs[row * 264 + col] = f2bfu(v > 0.f ? v : 0.f);
                }
        }
        __syncthreads();   // C: hs complete; red/xs free for next tile

        // 6) L2 MFMA: waves 0..3 each own rows wave*16..+15, full K=256, direct stores.
        //    Waves 4..7 fall through to next tile's convert/prefetch (overlap).
        if (wave < 4) {
            v4f a2 = (v4f){0.f, 0.f, 0.f, 0.f};
            #pragma unroll
            for (int kt = 0; kt < 8; kt++) {
                v8s av = *(const v8s*)(&hs[(wave * 16 + l15) * 264 + kt * 32 + quad * 8]);
                a2 = MFMA16(av, B2[kt], a2);
            }
            if (l15 < 6) {
                #pragma unroll
                for (int r = 0; r < 4; r++) {
                    const int row = wave * 16 + quad * 4 + r;
                    const int g = (row < 32) ? gA : gB;
                    const int n = g * NPG_ + (row & 31);
                    const float v = a2[r] + bias2;
                    if (l15 < HDN_) out[OFF_NH + n * HDN_ + l15] = v;
                    else            out[OFF_NV + n * HDN_ + (l15 - HDN_)] = v * v;
                }
            }
        }
        // no trailing barrier: next hs writes happen only after next barrier A,
        // by which point this L2's ds-reads have drained (lgkmcnt at barrier).
    }
}

// ---- graph MLP, all-MFMA — R7-verbatim (proven) ----
__global__ __launch_bounds__(256) void graph_mfma2(const unsigned short* __restrict__ xg,
                                                   const int* __restrict__ dsname,
                                                   const unsigned short* __restrict__ WgsT,
                                                   const float* __restrict__ bgs,
                                                   const unsigned short* __restrict__ WghP,
                                                   const float* __restrict__ bgh,
                                                   float* __restrict__ out) {
    __shared__ __align__(16) unsigned short xs[32 * 264];
    __shared__ int bls[32];
    const int gbase = blockIdx.x * 32;
    const int t = threadIdx.x;
    const int wave = t >> 6, lane = t & 63;
    const int l15 = lane & 15, quad = lane >> 4;
    if (t < 32) bls[t] = dsname[gbase + t];

    #pragma unroll
    for (int k = 0; k < 4; k++) {
        const int flat = k * 2048 + t * 8;
        *(v8s*)(&xs[(flat >> 8) * 264 + (flat & 255)]) =
            *(const v8s*)(xg + (size_t)gbase * 256 + flat);
    }
    __syncthreads();

    v4f acc[2][8];
    #pragma unroll
    for (int mt = 0; mt < 2; mt++)
        #pragma unroll
        for (int nt = 0; nt < 8; nt++) acc[mt][nt] = (v4f){0.f, 0.f, 0.f, 0.f};

    const unsigned short* Ab = &xs[l15 * 264 + quad * 8];
    const unsigned short* Bb = WgsT + (wave * 128 + l15) * 256 + quad * 8;

    #pragma unroll
    for (int kt = 0; kt < 8; kt++) {
        const int ko = kt * 32;
        v8s a0 = *(const v8s*)(Ab + ko);
        v8s a1 = *(const v8s*)(Ab + 16 * 264 + ko);
        #pragma unroll
        for (int nt = 0; nt < 8; nt++) {
            v8s bv = *(const v8s*)(Bb + nt * 16 * 256 + ko);
            acc[0][nt] = MFMA16(a0, bv, acc[0][nt]);
            acc[1][nt] = MFMA16(a1, bv, acc[1][nt]);
        }
    }
    __syncthreads();

    {
        const int bw = wave >> 1;
        #pragma unroll
        for (int nt = 0; nt < 8; nt++) {
            const int sp = wave * 128 + nt * 16 + l15;
            const int s_local = sp & 255;
            const float bias = bgs[sp];
            #pragma unroll
            for (int mt = 0; mt < 2; mt++)
                #pragma unroll
                for (int r = 0; r < 4; r++) {
                    const int row = mt * 16 + quad * 4 + r;
                    if (bls[row] == bw) {
                        const float v = acc[mt][nt][r] + bias;
                        xs[row * 264 + s_local] = f2bfu(v > 0.f ? v : 0.f);
                    }
                }
        }
    }
    __syncthreads();

    v4f acc2[2][4];
    #pragma unroll
    for (int mt = 0; mt < 2; mt++)
        #pragma unroll
        for (int nt = 0; nt < 4; nt++) acc2[mt][nt] = (v4f){0.f, 0.f, 0.f, 0.f};

    const unsigned short* B2 = WghP + ((wave * 4) * 16 + l15) * 256 + quad * 8;
    #pragma unroll
    for (int kt = 0; kt < 8; kt++) {
        const int ko = kt * 32;
        v8s a0 = *(const v8s*)(&xs[l15 * 264 + ko + quad * 8]);
        v8s a1 = *(const v8s*)(&xs[(16 + l15) * 264 + ko + quad * 8]);
        #pragma unroll
        for (int nt = 0; nt < 4; nt++) {
            v8s bv = *(const v8s*)(B2 + nt * 16 * 256 + ko);
            acc2[0][nt] = MFMA16(a0, bv, acc2[0][nt]);
            acc2[1][nt] = MFMA16(a1, bv, acc2[1][nt]);
        }
    }

    #pragma unroll
    for (int nt = 0; nt < 4; nt++) {
        const int npp  = (wave * 4 + nt) * 16 + l15;
        const int bo   = npp >> 7, c = npp & 127;
        if (c < 2 * HDG_) {
            const float bias = bgh[bo * 2 * HDG_ + c];
            #pragma unroll
            for (int mt = 0; mt < 2; mt++)
                #pragma unroll
                for (int r = 0; r < 4; r++) {
                    const int row = mt * 16 + quad * 4 + r;
                    if (bls[row] == bo) {
                        const float o = acc2[mt][nt][r] + bias;
                        const int g = gbase + row;
                        if (c < HDG_) out[OFF_GH + g * HDG_ + c] = o;
                        else          out[OFF_GV + g * HDG_ + (c - HDG_)] = o * o;
                    }
                }
        }
    }
}

extern "C" void kernel_launch(void* const* d_in, const int* in_sizes, int n_in,
                              void* d_out, int out_size, void* d_ws, size_t ws_size,
                              hipStream_t stream) {
    const float* x      = (const float*)d_in[0];
    const int*   dsname = (const int*)d_in[1];
    // d_in[2] = batch: arange(N)//32 by construction; structure used directly.
    const float* Wgs = (const float*)d_in[3];
    const float* bgs = (const float*)d_in[4];
    const float* Wgh = (const float*)d_in[5];
    const float* bgh = (const float*)d_in[6];
    const float* Wn1 = (const float*)d_in[7];
    const float* bn1 = (const float*)d_in[8];
    const float* Wn2 = (const float*)d_in[9];
    const float* bn2 = (const float*)d_in[10];
    float* out = (float*)d_out;

    unsigned short* wsbuf = (unsigned short*)d_ws;
    unsigned short* Wn1T  = wsbuf;              // @0        (131072 u16)
    unsigned short* WgsT  = wsbuf + 131072;     // @262144B  (131072)
    unsigned short* WghP  = wsbuf + 262144;     // @524288B  (65536)
    unsigned short* Wn2b  = wsbuf + 327680;     // @655360B  (8192)
    unsigned short* xg    = wsbuf + 335872;     // @671744B  (1048576 u16, 2MB)
    int* glist = (int*)((char*)d_ws + 2768896); // 2*4096 ints
    int* gcnt  = (int*)((char*)d_ws + 2801664); // 2 ints

    prep       <<<1313,    256, 0, stream>>>(Wn1, Wgs, Wgh, Wn2, wsbuf, dsname, glist, gcnt);
    node_pers2 <<<256,     512, 0, stream>>>(x, glist, gcnt, Wn1T, bn1, Wn2b, bn2, xg, out);
    graph_mfma2<<<G_ / 32, 256, 0, stream>>>(xg, dsname, WgsT, bgs, WghP, bgh, out);
}